// Round 1
// baseline (4325.855 us; speedup 1.0000x reference)
//
#include <hip/hip_runtime.h>
#include <hip/hip_bf16.h>

// SentenceEmbedding: 3 parallel BiLSTM branches over embedded tokens + time maxpool.
// B=256, T=128, E=256, H=256, 4H=1024, V=32000. Output [256][1536] f32.

#define NB 256
#define NT 128
#define NE 256
#define NH 256
#define NG 1024  // 4H

using bf16x8 = __attribute__((ext_vector_type(8))) short;
using f32x4  = __attribute__((ext_vector_type(4))) float;

static __device__ __forceinline__ ushort f2bf(float f) {
  union { float f; unsigned u; } v; v.f = f;
  unsigned r = v.u + 0x7fffu + ((v.u >> 16) & 1u);   // RNE to bf16
  return (ushort)(r >> 16);
}

// ---------------- embed: x[t][b][e] = bf16(Emb[tokens[b][t]][e]) ----------------
__global__ void k_embed(const int* __restrict__ tok, const float* __restrict__ emb,
                        ushort* __restrict__ x) {
  const int wv = threadIdx.x >> 6, l = threadIdx.x & 63;
  const int row = (blockIdx.x << 2) + wv;      // row = t*256 + b
  const int t = row >> 8, b = row & 255;
  const int tk = tok[b * NT + t];
  const float4 v = *(const float4*)(emb + (size_t)tk * NE + (l << 2));
  ushort4 o;
  o.x = f2bf(v.x); o.y = f2bf(v.y); o.z = f2bf(v.z); o.w = f2bf(v.w);
  *(ushort4*)(x + (size_t)row * NE + (l << 2)) = o;
}

// ---------------- pack weights into MFMA B-fragment order ----------------
// pack[chain][kt][ct][lane][j] = WU_chain[k=kt*32+(lane>>4)*8+j][col=ct*16+(lane&15)]
// rows k<256 from W (x proj), k>=256 from U (h proj). chain = layer*2 + dir.
__global__ void k_pack(const float* __restrict__ Wf, const float* __restrict__ Uf,
                       const float* __restrict__ Wb, const float* __restrict__ Ub,
                       ushort* __restrict__ pack) {
  const int tid = blockIdx.x * 256 + threadIdx.x;   // 0..393215
  const int lane = tid & 63;
  const int ct   = (tid >> 6) & 63;
  const int kt   = (tid >> 12) & 15;
  const int chain = tid >> 16;
  const int ll = chain >> 1, dir = chain & 1;
  const int col = (ct << 4) + (lane & 15);
  const int k0  = (kt << 5) + ((lane >> 4) << 3);
  const float* W = (dir ? Wb : Wf) + (size_t)ll * NE * NG;
  const float* U = (dir ? Ub : Uf) + (size_t)ll * NH * NG;
  ushort v[8];
#pragma unroll
  for (int j = 0; j < 8; ++j) {
    const int k = k0 + j;
    const float val = (k < NE) ? W[(size_t)k * NG + col] : U[(size_t)(k - NE) * NG + col];
    v[j] = f2bf(val);
  }
  ushort4* dst = (ushort4*)(pack + (size_t)tid * 8);
  dst[0] = make_ushort4(v[0], v[1], v[2], v[3]);
  dst[1] = make_ushort4(v[4], v[5], v[6], v[7]);
}

// ---------------- fused recurrent kernel ----------------
// 96 WGs: chain(6) x batch-tile(16). 512 thr = 8 waves; wave wv owns cols
// {g*256 + wv*32 + s*16 + (lane&15)} for g in 0..3 (i,f,g,o), s in 0..1 ->
// all 4 gates of an h-dim land in the same lane/reg => element-wise gate math.
__global__ __launch_bounds__(512, 2) void k_lstm(
    const ushort* __restrict__ x, const ushort* __restrict__ pack,
    const float* __restrict__ bf_, const float* __restrict__ bb_,
    float* __restrict__ out) {
  __shared__ float4 smem4[2048];                 // 32 KB: 2 bufs x (x 8K | h 8K)
  char* smem = (char*)smem4;

  // XCD-locality swizzle: 12 consecutive work items per XCD => <=2 chains/XCD L2
  const int bid = blockIdx.x;
  const int w = (bid & 7) * 12 + (bid >> 3);
  const int chain = w >> 4, tile = w & 15;
  const int ll = chain >> 1, dir = chain & 1;
  const int b0 = tile << 4;
  const int wv = threadIdx.x >> 6, lane = threadIdx.x & 63;

  const float* bias = (dir ? bb_ : bf_) + ll * NG;
  float bias_r[4][2];
  const ushort* bp[4][2];
#pragma unroll
  for (int g = 0; g < 4; ++g)
#pragma unroll
    for (int s = 0; s < 2; ++s) {
      const int ct = (g << 4) + (wv << 1) + s;
      bias_r[g][s] = bias[(g << 8) + (wv << 5) + (s << 4) + (lane & 15)];
      bp[g][s] = pack + (((size_t)chain * 1024 + ct) * 64 + lane) * 8;
    }

  // staging geometry: wave stages rows {2wv, 2wv+1}, 32 x 16B chunks per row
  const int rowit = (wv << 1) + (lane >> 5);
  const int slot = lane & 31;

  // init: h(buf0)=0, stage x_t0 into buf0.x (XOR-swizzled chunks)
  {
    const int t0 = dir ? (NT - 1) : 0;
    const bf16x8 x0 = *(const bf16x8*)(x + ((size_t)(t0 * NB + b0 + rowit) << 8) + (slot << 3));
    *(bf16x8*)(smem + rowit * 512 + ((slot ^ (rowit & 7)) << 4)) = x0;
    *(float4*)(smem + 8192 + threadIdx.x * 16) = make_float4(0.f, 0.f, 0.f, 0.f);
  }
  __syncthreads();

  float cc[2][4], hm[2][4];
#pragma unroll
  for (int s = 0; s < 2; ++s)
#pragma unroll
    for (int r = 0; r < 4; ++r) { cc[s][r] = 0.f; hm[s][r] = -1e30f; }

  int cur = 0;
  for (int t = 0; t < NT; ++t) {
    // T14: issue next x tile load early; LDS-write after compute
    bf16x8 xnext;
    const bool hasnext = (t + 1 < NT);
    if (hasnext) {
      const int tn = dir ? (NT - 2 - t) : (t + 1);
      xnext = *(const bf16x8*)(x + ((size_t)(tn * NB + b0 + rowit) << 8) + (slot << 3));
    }

    f32x4 acc[4][2];
#pragma unroll
    for (int g = 0; g < 4; ++g)
#pragma unroll
      for (int s = 0; s < 2; ++s) {
        const float bz = bias_r[g][s];
        acc[g][s] = (f32x4){bz, bz, bz, bz};
      }

    const char* abase = smem + (cur ? 16384 : 0);
    const int row = lane & 15;
    for (int kt = 0; kt < 16; ++kt) {
      const int chunk = ((kt & 7) << 2) + (lane >> 4);
      const bf16x8 a = *(const bf16x8*)(abase + ((kt & 8) << 10) + row * 512 +
                                        ((chunk ^ (row & 7)) << 4));
      const int koff = kt * 32768;  // 64 KB per kt, in ushorts
#pragma unroll
      for (int g = 0; g < 4; ++g)
#pragma unroll
        for (int s = 0; s < 2; ++s) {
          const bf16x8 bv = *(const bf16x8*)(bp[g][s] + koff);
          acc[g][s] = __builtin_amdgcn_mfma_f32_16x16x32_bf16(a, bv, acc[g][s], 0, 0, 0);
        }
    }

    char* nbase = smem + (cur ? 0 : 16384);
#pragma unroll
    for (int s = 0; s < 2; ++s)
#pragma unroll
      for (int r = 0; r < 4; ++r) {
        const float zi = acc[0][s][r], zf = acc[1][s][r];
        const float zg = acc[2][s][r], zo = acc[3][s][r];
        const float iv = 1.f / (1.f + __expf(-zi));
        const float fv = 1.f / (1.f + __expf(-zf));
        const float ov = 1.f / (1.f + __expf(-zo));
        const float gv = 1.f - 2.f / (__expf(2.f * zg) + 1.f);   // tanh
        const float c = fv * cc[s][r] + iv * gv;
        cc[s][r] = c;
        const float th = 1.f - 2.f / (__expf(2.f * c) + 1.f);
        const float hv = ov * th;
        hm[s][r] = fmaxf(hm[s][r], hv);
        const int rrow = ((lane >> 4) << 2) + r;
        const int hdim = (wv << 5) + (s << 4) + (lane & 15);
        const int byte = rrow * 512 + ((((hdim >> 3)) ^ (rrow & 7)) << 4) + ((hdim & 7) << 1);
        *(ushort*)(nbase + 8192 + byte) = f2bf(hv);
      }
    if (hasnext)
      *(bf16x8*)(nbase + rowit * 512 + ((slot ^ (rowit & 7)) << 4)) = xnext;
    __syncthreads();
    cur ^= 1;
  }

  // maxpool result: out[b][ll*512 + dir*256 + hdim]
#pragma unroll
  for (int s = 0; s < 2; ++s)
#pragma unroll
    for (int r = 0; r < 4; ++r) {
      const int b = b0 + ((lane >> 4) << 2) + r;
      const int col = ll * 512 + dir * 256 + (wv << 5) + (s << 4) + (lane & 15);
      out[(size_t)b * 1536 + col] = hm[s][r];
    }
}

extern "C" void kernel_launch(void* const* d_in, const int* in_sizes, int n_in,
                              void* d_out, int out_size, void* d_ws, size_t ws_size,
                              hipStream_t stream) {
  (void)in_sizes; (void)n_in; (void)out_size; (void)ws_size;
  const int*   tokens = (const int*)d_in[0];
  const float* Emb    = (const float*)d_in[1];
  const float* Wf     = (const float*)d_in[2];
  const float* Uf     = (const float*)d_in[3];
  const float* bf_    = (const float*)d_in[4];
  const float* Wb     = (const float*)d_in[5];
  const float* Ub     = (const float*)d_in[6];
  const float* bb_    = (const float*)d_in[7];
  float* out = (float*)d_out;

  ushort* x    = (ushort*)d_ws;                                   // 16 MB
  ushort* pack = (ushort*)((char*)d_ws + (size_t)NT * NB * NE * 2); // +6 MB

  hipLaunchKernelGGL(k_embed, dim3((NB * NT) / 4), dim3(256), 0, stream, tokens, Emb, x);
  hipLaunchKernelGGL(k_pack, dim3(1536), dim3(256), 0, stream, Wf, Uf, Wb, Ub, pack);
  hipLaunchKernelGGL(k_lstm, dim3(96), dim3(512), 0, stream, x, pack, bf_, bb_, out);
}

// Round 2
// 1272.823 us; speedup vs baseline: 3.3986x; 3.3986x over previous
//
#include <hip/hip_runtime.h>
#include <hip/hip_bf16.h>

// SentenceEmbedding: 3 parallel BiLSTM branches + time maxpool.
// B=256, T=128, E=256, H=256, 4H=1024. Output [256][1536] f32.
//
// R2 design: weight-RESIDENT recurrence.
//  - 192 WGs = 6 chains x 8 col-groups (32 h-dims) x 4 batch-groups (64 rows).
//  - U^T slice (32KB) lives in VGPRs (128 regs/lane), W^T slice (64KB) in LDS.
//  - Transposed MFMA: z^T[gatecol][b] = W^T|U^T (A) x x^T|h^T (B).
//    Acc quad regs = the 4 gates of one (b,hd) cell -> in-lane gate math.
//  - Per-step cross-WG h-slice exchange via global hbuf (B-frag order) +
//    per-(chain,bgroup) arrival counters, agent-scope release/acquire.
//  - Co-residency guaranteed: 128KB LDS => 1 WG/CU, grid 192 < 256 CUs.

#define NB 256
#define NT 128
#define NE 256
#define NH 256
#define NG 1024

using bf16x8 = __attribute__((ext_vector_type(8))) short;
using f32x4  = __attribute__((ext_vector_type(4))) float;

// ws layout (bytes)
#define X_OFF   0u           // 16 MB  bf16 x[t][b][e]
#define WT_OFF  16777216u    // 3 MB   W^T A-frag pack
#define UT_OFF  19922944u    // 3 MB   U^T A-frag pack
#define HB_OFF  23068672u    // 1.5 MB h exchange (2 parities)
#define CNT_OFF 24641536u    // 12 KB  arrival counters
#define HB_PAR_US 393216     // ushorts per parity
#define HB_GRP_US 16384      // ushorts per (chain,bg) slice

static __device__ __forceinline__ ushort f2bf(float f) {
  union { float f; unsigned u; } v; v.f = f;
  unsigned r = v.u + 0x7fffu + ((v.u >> 16) & 1u);   // RNE
  return (ushort)(r >> 16);
}
static __device__ __forceinline__ float sigf(float x) { return 1.f / (1.f + __expf(-x)); }
static __device__ __forceinline__ float tanhf_(float x) { return 1.f - 2.f / (__expf(2.f * x) + 1.f); }

// ---------------- embed: x[t][b][e] = bf16(Emb[tokens[b][t]][e]) ----------------
__global__ void k_embed(const int* __restrict__ tok, const float* __restrict__ emb,
                        ushort* __restrict__ x) {
  const int wv = threadIdx.x >> 6, l = threadIdx.x & 63;
  const int row = (blockIdx.x << 2) + wv;      // row = t*256 + b
  const int t = row >> 8, b = row & 255;
  const int tk = tok[b * NT + t];
  const float4 v = *(const float4*)(emb + (size_t)tk * NE + (l << 2));
  ushort4 o;
  o.x = f2bf(v.x); o.y = f2bf(v.y); o.z = f2bf(v.z); o.w = f2bf(v.w);
  *(ushort4*)(x + (size_t)row * NE + (l << 2)) = o;
}

// ---------------- pack W^T / U^T into MFMA A-fragment order ----------------
// A-frag (16x16x32): m = lane&15, k = (lane>>4)*8 + j.
// M-order within cg: ml = hdl*4 + g  (hdl in 0..31, g in 0..3) so that the
// D-frag's 4 regs (m = (lane>>4)*4 + r) are the 4 gates of one h-dim.
// pack[chain][cg][kt][mt][lane][j] = M[k = kt*32+(lane>>4)*8+j][col = g*256+cg*32+hdl]
__global__ void k_pack(const float* __restrict__ Wf, const float* __restrict__ Uf,
                       const float* __restrict__ Wb, const float* __restrict__ Ub,
                       ushort* __restrict__ wt, ushort* __restrict__ ut) {
  const int tid = blockIdx.x * 256 + threadIdx.x;   // 0..196607
  const int l = tid & 63;
  const int mt = (tid >> 6) & 7;
  const int kt = (tid >> 9) & 7;
  const int cg = (tid >> 12) & 7;
  const int chain = tid >> 15;                      // 0..5
  const int ll = chain >> 1, dir = chain & 1;
  const int ml = mt * 16 + (l & 15);
  const int hdl = ml >> 2, g = ml & 3;
  const int col = g * 256 + cg * 32 + hdl;
  const int k0 = kt * 32 + ((l >> 4) << 3);
  const float* W = (dir ? Wb : Wf) + (size_t)ll * NE * NG;
  const float* U = (dir ? Ub : Uf) + (size_t)ll * NH * NG;
  ushort vw[8], vu[8];
#pragma unroll
  for (int j = 0; j < 8; ++j) {
    vw[j] = f2bf(W[(size_t)(k0 + j) * NG + col]);
    vu[j] = f2bf(U[(size_t)(k0 + j) * NG + col]);
  }
  ushort4* dw = (ushort4*)(wt + (size_t)tid * 8);
  dw[0] = make_ushort4(vw[0], vw[1], vw[2], vw[3]);
  dw[1] = make_ushort4(vw[4], vw[5], vw[6], vw[7]);
  ushort4* du = (ushort4*)(ut + (size_t)tid * 8);
  du[0] = make_ushort4(vu[0], vu[1], vu[2], vu[3]);
  du[1] = make_ushort4(vu[4], vu[5], vu[6], vu[7]);
}

// ---------------- zero hbuf + counters (graph-replay safe) ----------------
__global__ void k_init(uint4* __restrict__ p) {   // zeros 1585152 B
  p[blockIdx.x * 256 + threadIdx.x] = make_uint4(0, 0, 0, 0);
}

// ---------------- recurrent kernel: 192 WGs x 512 thr ----------------
__global__ __launch_bounds__(512, 2) void k_lstm(
    const ushort* __restrict__ x, const ushort* __restrict__ wt,
    const ushort* __restrict__ ut, const float* __restrict__ bf_,
    const float* __restrict__ bb_, ushort* __restrict__ hbuf,
    uint* __restrict__ cnt, float* __restrict__ out) {
  __shared__ __align__(16) char smem[131072];
  // W_lds @0 (64KB frag-linear) | X_lds @65536 (32KB swizzled rows) | H_lds @98304 (32KB frag-linear)

  const int bid = blockIdx.x;
  const int w = (bid & 7) * 24 + (bid >> 3);     // XCD chunking: 3 groups/XCD
  const int cg = w & 7, grp = w >> 3;            // grp = chain*4 + bg
  const int chain = grp >> 2, bg = grp & 3;
  const int ll = chain >> 1, dir = chain & 1;
  const int b0 = bg << 6;
  const int tx = threadIdx.x;
  const int wv = tx >> 6, lane = tx & 63;
  const int mh = wv & 1, nt = wv >> 1;           // wave: m-half (16 h-dims), b-subtile (16 rows)

  // ---- preload W^T slice -> LDS (linear 64KB) ----
  {
    const bf16x8* wsrc = (const bf16x8*)(wt + (size_t)(chain * 8 + cg) * 32768);
    bf16x8* wdst = (bf16x8*)smem;
#pragma unroll
    for (int i = 0; i < 8; ++i) wdst[i * 512 + tx] = wsrc[i * 512 + tx];
  }

  // ---- preload U^T slice -> VGPRs (128 regs, fully static indexing) ----
  bf16x8 uf[8][4];
#pragma unroll
  for (int kt = 0; kt < 8; ++kt)
#pragma unroll
    for (int q = 0; q < 4; ++q)
      uf[kt][q] = *(const bf16x8*)(ut + ((size_t)(((chain * 8 + cg) * 8 + kt) * 8) + mh * 4 + q) * 512 + lane * 8);

  // ---- bias: acc reg r = gate r of h-dim hdl ----
  const float* bias = (dir ? bb_ : bf_) + ll * NG;
  float bias_r[4][4];
#pragma unroll
  for (int q = 0; q < 4; ++q)
#pragma unroll
    for (int r = 0; r < 4; ++r)
      bias_r[q][r] = bias[r * 256 + cg * 32 + mh * 16 + q * 4 + (lane >> 4)];

  float c_[4] = {0.f, 0.f, 0.f, 0.f};
  float hm[4] = {-1e30f, -1e30f, -1e30f, -1e30f};

  const int xrow = tx >> 3;          // staging: row 0..63
  const int xc0 = (tx & 7) * 4;      // 4 x 16B chunks per thread
  const int grp_us = grp * HB_GRP_US;
  uint* cgrp = cnt + grp * 128;

  for (int tau = 0; tau < NT; ++tau) {
    // ---- wait for all 8 cg-WGs of this (chain,bg) to publish h_{tau-1} ----
    if (tau > 0 && tx == 0) {
      const uint* cp = cgrp + (tau - 1);
      while (__hip_atomic_load(cp, __ATOMIC_ACQUIRE, __HIP_MEMORY_SCOPE_AGENT) < 8u)
        __builtin_amdgcn_s_sleep(8);
    }
    __syncthreads();

    // ---- stage h_{tau-1} (B-frag order: straight 32KB copy) ----
    {
      const bf16x8* hsrc = (const bf16x8*)(hbuf + (size_t)(tau & 1) * HB_PAR_US + grp_us);
      bf16x8* hdst = (bf16x8*)(smem + 98304);
#pragma unroll
      for (int i = 0; i < 4; ++i) hdst[i * 512 + tx] = hsrc[i * 512 + tx];
    }
    // ---- stage x_t (row-major, XOR-swizzled 16B chunks) ----
    {
      const int t = dir ? (NT - 1 - tau) : tau;
      const ushort* xs = x + ((size_t)t * NB + b0 + xrow) * NE;
#pragma unroll
      for (int cc = 0; cc < 4; ++cc) {
        const int c = xc0 + cc;
        bf16x8 v = *(const bf16x8*)(xs + c * 8);
        *(bf16x8*)(smem + 65536 + xrow * 512 + ((c ^ (xrow & 7)) << 4)) = v;
      }
    }
    __syncthreads();

    // ---- z^T = W^T x^T + U^T h^T + b ----
    f32x4 acc[4];
#pragma unroll
    for (int q = 0; q < 4; ++q)
      acc[q] = (f32x4){bias_r[q][0], bias_r[q][1], bias_r[q][2], bias_r[q][3]};

    const int brow = nt * 16 + (lane & 15);
#pragma unroll
    for (int kt = 0; kt < 8; ++kt) {
      const int xch = kt * 4 + (lane >> 4);
      const bf16x8 xB = *(const bf16x8*)(smem + 65536 + brow * 512 + ((xch ^ (brow & 7)) << 4));
      const bf16x8 hB = *(const bf16x8*)(smem + 98304 + ((kt * 4 + nt) * 64 + lane) * 16);
#pragma unroll
      for (int q = 0; q < 4; ++q) {
        const bf16x8 wA = *(const bf16x8*)(smem + ((kt * 8 + mh * 4 + q) * 64 + lane) * 16);
        acc[q] = __builtin_amdgcn_mfma_f32_16x16x32_bf16(wA, xB, acc[q], 0, 0, 0);
        acc[q] = __builtin_amdgcn_mfma_f32_16x16x32_bf16(uf[kt][q], hB, acc[q], 0, 0, 0);
      }
    }

    // ---- gates (in-lane: acc[q][r] = gate r of (b,hd) cell), publish h ----
    ushort* hw = hbuf + (size_t)((tau + 1) & 1) * HB_PAR_US + grp_us + (cg * 4 + nt) * 512;
#pragma unroll
    for (int q = 0; q < 4; ++q) {
      const float iv = sigf(acc[q][0]);
      const float fv = sigf(acc[q][1]);
      const float gv = tanhf_(acc[q][2]);
      const float ov = sigf(acc[q][3]);
      const float cn = fv * c_[q] + iv * gv;
      c_[q] = cn;
      const float hv = ov * tanhf_(cn);
      hm[q] = fmaxf(hm[q], hv);
      const int hdl = mh * 16 + q * 4 + (lane >> 4);
      const int lane2 = (lane & 15) | ((hdl >> 3) << 4);
      hw[lane2 * 8 + (hdl & 7)] = f2bf(hv);     // B-frag order for next step
    }
    __syncthreads();   // drains vmcnt per wave before barrier -> stores in L2
    if (tx == 0)
      __hip_atomic_fetch_add(cgrp + tau, 1u, __ATOMIC_RELEASE, __HIP_MEMORY_SCOPE_AGENT);
  }

  // ---- maxpool output: out[b][ll*512 + dir*256 + hd] ----
#pragma unroll
  for (int q = 0; q < 4; ++q) {
    const int b = b0 + nt * 16 + (lane & 15);
    const int col = ll * 512 + dir * 256 + cg * 32 + mh * 16 + q * 4 + (lane >> 4);
    out[(size_t)b * 1536 + col] = hm[q];
  }
}

extern "C" void kernel_launch(void* const* d_in, const int* in_sizes, int n_in,
                              void* d_out, int out_size, void* d_ws, size_t ws_size,
                              hipStream_t stream) {
  (void)in_sizes; (void)n_in; (void)out_size; (void)ws_size;
  const int*   tokens = (const int*)d_in[0];
  const float* Emb    = (const float*)d_in[1];
  const float* Wf     = (const float*)d_in[2];
  const float* Uf     = (const float*)d_in[3];
  const float* bf_    = (const float*)d_in[4];
  const float* Wb     = (const float*)d_in[5];
  const float* Ub     = (const float*)d_in[6];
  const float* bb_    = (const float*)d_in[7];
  float* out = (float*)d_out;

  ushort* x    = (ushort*)((char*)d_ws + X_OFF);
  ushort* wt   = (ushort*)((char*)d_ws + WT_OFF);
  ushort* ut   = (ushort*)((char*)d_ws + UT_OFF);
  ushort* hbuf = (ushort*)((char*)d_ws + HB_OFF);
  uint*   cnt  = (uint*)((char*)d_ws + CNT_OFF);

  hipLaunchKernelGGL(k_embed, dim3((NB * NT) / 4), dim3(256), 0, stream, tokens, Emb, x);
  hipLaunchKernelGGL(k_pack, dim3(768), dim3(256), 0, stream, Wf, Uf, Wb, Ub, wt, ut);
  hipLaunchKernelGGL(k_init, dim3(387), dim3(256), 0, stream, (uint4*)hbuf);
  hipLaunchKernelGGL(k_lstm, dim3(192), dim3(512), 0, stream, x, wt, ut, bf_, bb_, hbuf, cnt, out);
}

// Round 3
// 1271.716 us; speedup vs baseline: 3.4016x; 1.0009x over previous
//
#include <hip/hip_runtime.h>
#include <hip/hip_bf16.h>

// SentenceEmbedding: 3 parallel BiLSTM branches + time maxpool.
// B=256, T=128, E=256, H=256, 4H=1024. Output [256][1536] f32.
//
// R2 design: weight-RESIDENT recurrence.
//  - 192 WGs = 6 chains x 8 col-groups (32 h-dims) x 4 batch-groups (64 rows).
//  - U^T slice (32KB) lives in VGPRs (128 regs/lane), W^T slice (64KB) in LDS.
//  - Transposed MFMA: z^T[gatecol][b] = W^T|U^T (A) x x^T|h^T (B).
//    Acc quad regs = the 4 gates of one (b,hd) cell -> in-lane gate math.
//  - Per-step cross-WG h-slice exchange via global hbuf (B-frag order) +
//    per-(chain,bgroup) arrival counters, agent-scope release/acquire.
//  - Co-residency guaranteed: 128KB LDS => 1 WG/CU, grid 192 < 256 CUs.

#define NB 256
#define NT 128
#define NE 256
#define NH 256
#define NG 1024

using bf16x8 = __attribute__((ext_vector_type(8))) short;
using f32x4  = __attribute__((ext_vector_type(4))) float;

// ws layout (bytes)
#define X_OFF   0u           // 16 MB  bf16 x[t][b][e]
#define WT_OFF  16777216u    // 3 MB   W^T A-frag pack
#define UT_OFF  19922944u    // 3 MB   U^T A-frag pack
#define HB_OFF  23068672u    // 1.5 MB h exchange (2 parities)
#define CNT_OFF 24641536u    // 12 KB  arrival counters
#define HB_PAR_US 393216     // ushorts per parity
#define HB_GRP_US 16384      // ushorts per (chain,bg) slice

static __device__ __forceinline__ ushort f2bf(float f) {
  union { float f; unsigned u; } v; v.f = f;
  unsigned r = v.u + 0x7fffu + ((v.u >> 16) & 1u);   // RNE
  return (ushort)(r >> 16);
}
static __device__ __forceinline__ float sigf(float x) { return 1.f / (1.f + __expf(-x)); }
static __device__ __forceinline__ float tanhf_(float x) { return 1.f - 2.f / (__expf(2.f * x) + 1.f); }

// ---------------- embed: x[t][b][e] = bf16(Emb[tokens[b][t]][e]) ----------------
__global__ void k_embed(const int* __restrict__ tok, const float* __restrict__ emb,
                        ushort* __restrict__ x) {
  const int wv = threadIdx.x >> 6, l = threadIdx.x & 63;
  const int row = (blockIdx.x << 2) + wv;      // row = t*256 + b
  const int t = row >> 8, b = row & 255;
  const int tk = tok[b * NT + t];
  const float4 v = *(const float4*)(emb + (size_t)tk * NE + (l << 2));
  ushort4 o;
  o.x = f2bf(v.x); o.y = f2bf(v.y); o.z = f2bf(v.z); o.w = f2bf(v.w);
  *(ushort4*)(x + (size_t)row * NE + (l << 2)) = o;
}

// ---------------- pack W^T / U^T into MFMA A-fragment order ----------------
// A-frag (16x16x32): m = lane&15, k = (lane>>4)*8 + j.
// M-order within cg: ml = hdl*4 + g  (hdl in 0..31, g in 0..3) so that the
// D-frag's 4 regs (m = (lane>>4)*4 + r) are the 4 gates of one h-dim.
// pack[chain][cg][kt][mt][lane][j] = M[k = kt*32+(lane>>4)*8+j][col = g*256+cg*32+hdl]
__global__ void k_pack(const float* __restrict__ Wf, const float* __restrict__ Uf,
                       const float* __restrict__ Wb, const float* __restrict__ Ub,
                       ushort* __restrict__ wt, ushort* __restrict__ ut) {
  const int tid = blockIdx.x * 256 + threadIdx.x;   // 0..196607
  const int l = tid & 63;
  const int mt = (tid >> 6) & 7;
  const int kt = (tid >> 9) & 7;
  const int cg = (tid >> 12) & 7;
  const int chain = tid >> 15;                      // 0..5
  const int ll = chain >> 1, dir = chain & 1;
  const int ml = mt * 16 + (l & 15);
  const int hdl = ml >> 2, g = ml & 3;
  const int col = g * 256 + cg * 32 + hdl;
  const int k0 = kt * 32 + ((l >> 4) << 3);
  const float* W = (dir ? Wb : Wf) + (size_t)ll * NE * NG;
  const float* U = (dir ? Ub : Uf) + (size_t)ll * NH * NG;
  ushort vw[8], vu[8];
#pragma unroll
  for (int j = 0; j < 8; ++j) {
    vw[j] = f2bf(W[(size_t)(k0 + j) * NG + col]);
    vu[j] = f2bf(U[(size_t)(k0 + j) * NG + col]);
  }
  ushort4* dw = (ushort4*)(wt + (size_t)tid * 8);
  dw[0] = make_ushort4(vw[0], vw[1], vw[2], vw[3]);
  dw[1] = make_ushort4(vw[4], vw[5], vw[6], vw[7]);
  ushort4* du = (ushort4*)(ut + (size_t)tid * 8);
  du[0] = make_ushort4(vu[0], vu[1], vu[2], vu[3]);
  du[1] = make_ushort4(vu[4], vu[5], vu[6], vu[7]);
}

// ---------------- zero hbuf + counters (graph-replay safe) ----------------
__global__ void k_init(uint4* __restrict__ p) {   // zeros 1585152 B
  p[blockIdx.x * 256 + threadIdx.x] = make_uint4(0, 0, 0, 0);
}

// ---------------- recurrent kernel: 192 WGs x 512 thr ----------------
__global__ __launch_bounds__(512, 2) void k_lstm(
    const ushort* __restrict__ x, const ushort* __restrict__ wt,
    const ushort* __restrict__ ut, const float* __restrict__ bf_,
    const float* __restrict__ bb_, ushort* __restrict__ hbuf,
    uint* __restrict__ cnt, float* __restrict__ out) {
  __shared__ __align__(16) char smem[131072];
  // W_lds @0 (64KB frag-linear) | X_lds @65536 (32KB swizzled rows) | H_lds @98304 (32KB frag-linear)

  const int bid = blockIdx.x;
  const int w = (bid & 7) * 24 + (bid >> 3);     // XCD chunking: 3 groups/XCD
  const int cg = w & 7, grp = w >> 3;            // grp = chain*4 + bg
  const int chain = grp >> 2, bg = grp & 3;
  const int ll = chain >> 1, dir = chain & 1;
  const int b0 = bg << 6;
  const int tx = threadIdx.x;
  const int wv = tx >> 6, lane = tx & 63;
  const int mh = wv & 1, nt = wv >> 1;           // wave: m-half (16 h-dims), b-subtile (16 rows)

  // ---- preload W^T slice -> LDS (linear 64KB) ----
  {
    const bf16x8* wsrc = (const bf16x8*)(wt + (size_t)(chain * 8 + cg) * 32768);
    bf16x8* wdst = (bf16x8*)smem;
#pragma unroll
    for (int i = 0; i < 8; ++i) wdst[i * 512 + tx] = wsrc[i * 512 + tx];
  }

  // ---- preload U^T slice -> VGPRs (128 regs, fully static indexing) ----
  bf16x8 uf[8][4];
#pragma unroll
  for (int kt = 0; kt < 8; ++kt)
#pragma unroll
    for (int q = 0; q < 4; ++q)
      uf[kt][q] = *(const bf16x8*)(ut + ((size_t)(((chain * 8 + cg) * 8 + kt) * 8) + mh * 4 + q) * 512 + lane * 8);

  // ---- bias: acc reg r = gate r of h-dim hdl ----
  const float* bias = (dir ? bb_ : bf_) + ll * NG;
  float bias_r[4][4];
#pragma unroll
  for (int q = 0; q < 4; ++q)
#pragma unroll
    for (int r = 0; r < 4; ++r)
      bias_r[q][r] = bias[r * 256 + cg * 32 + mh * 16 + q * 4 + (lane >> 4)];

  float c_[4] = {0.f, 0.f, 0.f, 0.f};
  float hm[4] = {-1e30f, -1e30f, -1e30f, -1e30f};

  const int xrow = tx >> 3;          // staging: row 0..63
  const int xc0 = (tx & 7) * 4;      // 4 x 16B chunks per thread
  const int grp_us = grp * HB_GRP_US;
  uint* cgrp = cnt + grp * 128;

  for (int tau = 0; tau < NT; ++tau) {
    // ---- wait for all 8 cg-WGs of this (chain,bg) to publish h_{tau-1} ----
    if (tau > 0 && tx == 0) {
      const uint* cp = cgrp + (tau - 1);
      while (__hip_atomic_load(cp, __ATOMIC_ACQUIRE, __HIP_MEMORY_SCOPE_AGENT) < 8u)
        __builtin_amdgcn_s_sleep(8);
    }
    __syncthreads();

    // ---- stage h_{tau-1} (B-frag order: straight 32KB copy) ----
    {
      const bf16x8* hsrc = (const bf16x8*)(hbuf + (size_t)(tau & 1) * HB_PAR_US + grp_us);
      bf16x8* hdst = (bf16x8*)(smem + 98304);
#pragma unroll
      for (int i = 0; i < 4; ++i) hdst[i * 512 + tx] = hsrc[i * 512 + tx];
    }
    // ---- stage x_t (row-major, XOR-swizzled 16B chunks) ----
    {
      const int t = dir ? (NT - 1 - tau) : tau;
      const ushort* xs = x + ((size_t)t * NB + b0 + xrow) * NE;
#pragma unroll
      for (int cc = 0; cc < 4; ++cc) {
        const int c = xc0 + cc;
        bf16x8 v = *(const bf16x8*)(xs + c * 8);
        *(bf16x8*)(smem + 65536 + xrow * 512 + ((c ^ (xrow & 7)) << 4)) = v;
      }
    }
    __syncthreads();

    // ---- z^T = W^T x^T + U^T h^T + b ----
    f32x4 acc[4];
#pragma unroll
    for (int q = 0; q < 4; ++q)
      acc[q] = (f32x4){bias_r[q][0], bias_r[q][1], bias_r[q][2], bias_r[q][3]};

    const int brow = nt * 16 + (lane & 15);
#pragma unroll
    for (int kt = 0; kt < 8; ++kt) {
      const int xch = kt * 4 + (lane >> 4);
      const bf16x8 xB = *(const bf16x8*)(smem + 65536 + brow * 512 + ((xch ^ (brow & 7)) << 4));
      const bf16x8 hB = *(const bf16x8*)(smem + 98304 + ((kt * 4 + nt) * 64 + lane) * 16);
#pragma unroll
      for (int q = 0; q < 4; ++q) {
        const bf16x8 wA = *(const bf16x8*)(smem + ((kt * 8 + mh * 4 + q) * 64 + lane) * 16);
        acc[q] = __builtin_amdgcn_mfma_f32_16x16x32_bf16(wA, xB, acc[q], 0, 0, 0);
        acc[q] = __builtin_amdgcn_mfma_f32_16x16x32_bf16(uf[kt][q], hB, acc[q], 0, 0, 0);
      }
    }

    // ---- gates (in-lane: acc[q][r] = gate r of (b,hd) cell), publish h ----
    ushort* hw = hbuf + (size_t)((tau + 1) & 1) * HB_PAR_US + grp_us + (cg * 4 + nt) * 512;
#pragma unroll
    for (int q = 0; q < 4; ++q) {
      const float iv = sigf(acc[q][0]);
      const float fv = sigf(acc[q][1]);
      const float gv = tanhf_(acc[q][2]);
      const float ov = sigf(acc[q][3]);
      const float cn = fv * c_[q] + iv * gv;
      c_[q] = cn;
      const float hv = ov * tanhf_(cn);
      hm[q] = fmaxf(hm[q], hv);
      const int hdl = mh * 16 + q * 4 + (lane >> 4);
      const int lane2 = (lane & 15) | ((hdl >> 3) << 4);
      hw[lane2 * 8 + (hdl & 7)] = f2bf(hv);     // B-frag order for next step
    }
    __syncthreads();   // drains vmcnt per wave before barrier -> stores in L2
    if (tx == 0)
      __hip_atomic_fetch_add(cgrp + tau, 1u, __ATOMIC_RELEASE, __HIP_MEMORY_SCOPE_AGENT);
  }

  // ---- maxpool output: out[b][ll*512 + dir*256 + hd] ----
#pragma unroll
  for (int q = 0; q < 4; ++q) {
    const int b = b0 + nt * 16 + (lane & 15);
    const int col = ll * 512 + dir * 256 + cg * 32 + mh * 16 + q * 4 + (lane >> 4);
    out[(size_t)b * 1536 + col] = hm[q];
  }
}

extern "C" void kernel_launch(void* const* d_in, const int* in_sizes, int n_in,
                              void* d_out, int out_size, void* d_ws, size_t ws_size,
                              hipStream_t stream) {
  (void)in_sizes; (void)n_in; (void)out_size; (void)ws_size;
  const int*   tokens = (const int*)d_in[0];
  const float* Emb    = (const float*)d_in[1];
  const float* Wf     = (const float*)d_in[2];
  const float* Uf     = (const float*)d_in[3];
  const float* bf_    = (const float*)d_in[4];
  const float* Wb     = (const float*)d_in[5];
  const float* Ub     = (const float*)d_in[6];
  const float* bb_    = (const float*)d_in[7];
  float* out = (float*)d_out;

  ushort* x    = (ushort*)((char*)d_ws + X_OFF);
  ushort* wt   = (ushort*)((char*)d_ws + WT_OFF);
  ushort* ut   = (ushort*)((char*)d_ws + UT_OFF);
  ushort* hbuf = (ushort*)((char*)d_ws + HB_OFF);
  uint*   cnt  = (uint*)((char*)d_ws + CNT_OFF);

  hipLaunchKernelGGL(k_embed, dim3((NB * NT) / 4), dim3(256), 0, stream, tokens, Emb, x);
  hipLaunchKernelGGL(k_pack, dim3(768), dim3(256), 0, stream, Wf, Uf, Wb, Ub, wt, ut);
  hipLaunchKernelGGL(k_init, dim3(387), dim3(256), 0, stream, (uint4*)hbuf);
  hipLaunchKernelGGL(k_lstm, dim3(192), dim3(512), 0, stream, x, wt, ut, bf_, bb_, hbuf, cnt, out);
}

// Round 4
// 530.587 us; speedup vs baseline: 8.1530x; 2.3968x over previous
//
#include <hip/hip_runtime.h>
#include <hip/hip_bf16.h>

// SentenceEmbedding: 3 parallel BiLSTM branches + time maxpool.
// B=256, T=128, E=256, H=256, 4H=1024. Output [256][1536] f32.
//
// R3: weight-resident recurrence with fence-free exchange.
//  - 192 WGs = 6 chains x 8 col-groups x 4 batch-groups; U in VGPR/AGPR,
//    W in LDS; transposed MFMA so the 4 acc regs = 4 gates of one cell.
//  - Cross-WG h exchange via RELAXED agent-scope atomics only (no
//    acquire/release fences -> no buffer_wbl2/inv per step). Ordering via
//    __syncthreads() vmcnt drain before the counter add.
//  - Latency hiding: W.x kt0-3 before the poll barrier; h-loads interleaved
//    with W.x kt4-7; x_{t+1} staged at the step tail.

#define NB 256
#define NT 128
#define NE 256
#define NH 256
#define NG 1024

using bf16x8 = __attribute__((ext_vector_type(8))) short;
using f32x4  = __attribute__((ext_vector_type(4))) float;
typedef unsigned long long u64;

// ws layout (bytes)
#define X_OFF   0u           // 16 MB  bf16 x[t][b][e]
#define WT_OFF  16777216u    // 3 MB   W^T A-frag pack
#define UT_OFF  19922944u    // 3 MB   U^T A-frag pack
#define HB_OFF  23068672u    // 1.5 MB h exchange (2 parities)
#define CNT_OFF 24641536u    // 12 KB  arrival counters
#define HB_PAR_US 393216     // ushorts per parity
#define HB_GRP_US 16384      // ushorts per (chain,bg) slice

static __device__ __forceinline__ ushort f2bf(float f) {
  union { float f; unsigned u; } v; v.f = f;
  unsigned r = v.u + 0x7fffu + ((v.u >> 16) & 1u);   // RNE
  return (ushort)(r >> 16);
}
static __device__ __forceinline__ float sigf(float x) { return 1.f / (1.f + __expf(-x)); }
static __device__ __forceinline__ float tanhf_(float x) { return 1.f - 2.f / (__expf(2.f * x) + 1.f); }

// ---------------- embed: x[t][b][e] = bf16(Emb[tokens[b][t]][e]) ----------------
__global__ void k_embed(const int* __restrict__ tok, const float* __restrict__ emb,
                        ushort* __restrict__ x) {
  const int wv = threadIdx.x >> 6, l = threadIdx.x & 63;
  const int row = (blockIdx.x << 2) + wv;      // row = t*256 + b
  const int t = row >> 8, b = row & 255;
  const int tk = tok[b * NT + t];
  const float4 v = *(const float4*)(emb + (size_t)tk * NE + (l << 2));
  ushort4 o;
  o.x = f2bf(v.x); o.y = f2bf(v.y); o.z = f2bf(v.z); o.w = f2bf(v.w);
  *(ushort4*)(x + (size_t)row * NE + (l << 2)) = o;
}

// ---------------- pack W^T / U^T into MFMA A-fragment order ----------------
// M-order within cg: ml = hdl*4 + g so the D-frag's 4 regs are the 4 gates
// of one h-dim. pack[chain][cg][kt][mt][lane][j].
__global__ void k_pack(const float* __restrict__ Wf, const float* __restrict__ Uf,
                       const float* __restrict__ Wb, const float* __restrict__ Ub,
                       ushort* __restrict__ wt, ushort* __restrict__ ut) {
  const int tid = blockIdx.x * 256 + threadIdx.x;   // 0..196607
  const int l = tid & 63;
  const int mt = (tid >> 6) & 7;
  const int kt = (tid >> 9) & 7;
  const int cg = (tid >> 12) & 7;
  const int chain = tid >> 15;                      // 0..5
  const int ll = chain >> 1, dir = chain & 1;
  const int ml = mt * 16 + (l & 15);
  const int hdl = ml >> 2, g = ml & 3;
  const int col = g * 256 + cg * 32 + hdl;
  const int k0 = kt * 32 + ((l >> 4) << 3);
  const float* W = (dir ? Wb : Wf) + (size_t)ll * NE * NG;
  const float* U = (dir ? Ub : Uf) + (size_t)ll * NH * NG;
  ushort vw[8], vu[8];
#pragma unroll
  for (int j = 0; j < 8; ++j) {
    vw[j] = f2bf(W[(size_t)(k0 + j) * NG + col]);
    vu[j] = f2bf(U[(size_t)(k0 + j) * NG + col]);
  }
  ushort4* dw = (ushort4*)(wt + (size_t)tid * 8);
  dw[0] = make_ushort4(vw[0], vw[1], vw[2], vw[3]);
  dw[1] = make_ushort4(vw[4], vw[5], vw[6], vw[7]);
  ushort4* du = (ushort4*)(ut + (size_t)tid * 8);
  du[0] = make_ushort4(vu[0], vu[1], vu[2], vu[3]);
  du[1] = make_ushort4(vu[4], vu[5], vu[6], vu[7]);
}

// ---------------- zero hbuf + counters (graph-replay safe) ----------------
__global__ void k_init(uint4* __restrict__ p) {   // zeros 1585152 B
  p[blockIdx.x * 256 + threadIdx.x] = make_uint4(0, 0, 0, 0);
}

// ---------------- recurrent kernel: 192 WGs x 512 thr ----------------
__global__ __launch_bounds__(512, 2) void k_lstm(
    const ushort* __restrict__ x, const ushort* __restrict__ wt,
    const ushort* __restrict__ ut, const float* __restrict__ bf_,
    const float* __restrict__ bb_, ushort* __restrict__ hbuf,
    uint* __restrict__ cnt, float* __restrict__ out) {
  __shared__ __align__(16) char smem[131072];
  // W @0 (64KB frag-linear) | X @65536 (32KB swizzled) | H @98304 (32KB frag-linear)

  const int bid = blockIdx.x;
  const int w = (bid & 7) * 24 + (bid >> 3);     // XCD chunking (perf-only)
  const int cg = w & 7, grp = w >> 3;            // grp = chain*4 + bg
  const int chain = grp >> 2, bg = grp & 3;
  const int ll = chain >> 1, dir = chain & 1;
  const int b0 = bg << 6;
  const int tx = threadIdx.x;
  const int wv = tx >> 6, lane = tx & 63;
  const int mh = wv & 1, nt = wv >> 1;

  // ---- preload W^T slice -> LDS ----
  {
    const bf16x8* wsrc = (const bf16x8*)(wt + (size_t)(chain * 8 + cg) * 32768);
    bf16x8* wdst = (bf16x8*)smem;
#pragma unroll
    for (int i = 0; i < 8; ++i) wdst[i * 512 + tx] = wsrc[i * 512 + tx];
  }
  // ---- preload U^T slice -> regs ----
  bf16x8 uf[8][4];
#pragma unroll
  for (int kt = 0; kt < 8; ++kt)
#pragma unroll
    for (int q = 0; q < 4; ++q)
      uf[kt][q] = *(const bf16x8*)(ut + ((size_t)(((chain * 8 + cg) * 8 + kt) * 8) + mh * 4 + q) * 512 + lane * 8);

  // ---- bias ----
  const float* bias = (dir ? bb_ : bf_) + ll * NG;
  float bias_r[4][4];
#pragma unroll
  for (int q = 0; q < 4; ++q)
#pragma unroll
    for (int r = 0; r < 4; ++r)
      bias_r[q][r] = bias[r * 256 + cg * 32 + mh * 16 + q * 4 + (lane >> 4)];

  float c_[4] = {0.f, 0.f, 0.f, 0.f};
  float hm[4] = {-1e30f, -1e30f, -1e30f, -1e30f};

  const int xrow = tx >> 3;
  const int grp_us = grp * HB_GRP_US;
  uint* cgrp = cnt + grp * 128;
  const int brow = nt * 16 + (lane & 15);

  // ---- prologue: stage x_0 ----
  {
    const int t0 = dir ? (NT - 1) : 0;
    const ushort* xs = x + ((size_t)t0 * NB + b0 + xrow) * NE + (tx & 7) * 8;
#pragma unroll
    for (int i = 0; i < 4; ++i) {
      bf16x8 v = *(const bf16x8*)(xs + i * 64);
      const int c = (tx & 7) + 8 * i;
      *(bf16x8*)(smem + 65536 + xrow * 512 + ((c ^ (xrow & 7)) << 4)) = v;
    }
  }
  __syncthreads();

  for (int tau = 0; tau < NT; ++tau) {
    f32x4 acc[4];
#pragma unroll
    for (int q = 0; q < 4; ++q)
      acc[q] = (f32x4){bias_r[q][0], bias_r[q][1], bias_r[q][2], bias_r[q][3]};

    // ---- W.x first half (no h dependency) ----
#pragma unroll
    for (int kt = 0; kt < 4; ++kt) {
      const int xch = kt * 4 + (lane >> 4);
      const bf16x8 xB = *(const bf16x8*)(smem + 65536 + brow * 512 + ((xch ^ (brow & 7)) << 4));
#pragma unroll
      for (int q = 0; q < 4; ++q) {
        const bf16x8 wA = *(const bf16x8*)(smem + ((kt * 8 + mh * 4 + q) * 64 + lane) * 16);
        acc[q] = __builtin_amdgcn_mfma_f32_16x16x32_bf16(wA, xB, acc[q], 0, 0, 0);
      }
    }

    // ---- wait for siblings' h_{tau-1} (relaxed poll, no fence) ----
    if (tau > 0 && tx == 0) {
      const uint* cp = cgrp + (tau - 1);
      while (__hip_atomic_load(cp, __ATOMIC_RELAXED, __HIP_MEMORY_SCOPE_AGENT) < 8u)
        __builtin_amdgcn_s_sleep(1);
    }
    __syncthreads();                                    // (1)

    // ---- h loads (batch A) + W.x kt4-5 ----
    u64* hd = (u64*)(smem + 98304);
    const u64* hs = (const u64*)(hbuf + (size_t)(tau & 1) * HB_PAR_US + grp_us);
    u64 hra[4], hrb[4];
    if (tau > 0) {
#pragma unroll
      for (int j = 0; j < 4; ++j)
        hra[j] = __hip_atomic_load(hs + ((j >> 1) * 1024 + (j & 1) * 512 + tx),
                                   __ATOMIC_RELAXED, __HIP_MEMORY_SCOPE_AGENT);
    } else {
#pragma unroll
      for (int j = 0; j < 4; ++j) hra[j] = 0ull;
    }
#pragma unroll
    for (int kt = 4; kt < 6; ++kt) {
      const int xch = kt * 4 + (lane >> 4);
      const bf16x8 xB = *(const bf16x8*)(smem + 65536 + brow * 512 + ((xch ^ (brow & 7)) << 4));
#pragma unroll
      for (int q = 0; q < 4; ++q) {
        const bf16x8 wA = *(const bf16x8*)(smem + ((kt * 8 + mh * 4 + q) * 64 + lane) * 16);
        acc[q] = __builtin_amdgcn_mfma_f32_16x16x32_bf16(wA, xB, acc[q], 0, 0, 0);
      }
    }
#pragma unroll
    for (int j = 0; j < 4; ++j)
      hd[(j >> 1) * 1024 + (j & 1) * 512 + tx] = hra[j];

    // ---- h loads (batch B) + W.x kt6-7 ----
    if (tau > 0) {
#pragma unroll
      for (int j = 4; j < 8; ++j)
        hrb[j - 4] = __hip_atomic_load(hs + ((j >> 1) * 1024 + (j & 1) * 512 + tx),
                                       __ATOMIC_RELAXED, __HIP_MEMORY_SCOPE_AGENT);
    } else {
#pragma unroll
      for (int j = 0; j < 4; ++j) hrb[j] = 0ull;
    }
#pragma unroll
    for (int kt = 6; kt < 8; ++kt) {
      const int xch = kt * 4 + (lane >> 4);
      const bf16x8 xB = *(const bf16x8*)(smem + 65536 + brow * 512 + ((xch ^ (brow & 7)) << 4));
#pragma unroll
      for (int q = 0; q < 4; ++q) {
        const bf16x8 wA = *(const bf16x8*)(smem + ((kt * 8 + mh * 4 + q) * 64 + lane) * 16);
        acc[q] = __builtin_amdgcn_mfma_f32_16x16x32_bf16(wA, xB, acc[q], 0, 0, 0);
      }
    }
#pragma unroll
    for (int j = 4; j < 8; ++j)
      hd[(j >> 1) * 1024 + (j & 1) * 512 + tx] = hrb[j - 4];
    __syncthreads();                                    // (2)

    // ---- U.h ----
#pragma unroll
    for (int kt = 0; kt < 8; ++kt) {
      const bf16x8 hB = *(const bf16x8*)(smem + 98304 + ((kt * 4 + nt) * 64 + lane) * 16);
#pragma unroll
      for (int q = 0; q < 4; ++q)
        acc[q] = __builtin_amdgcn_mfma_f32_16x16x32_bf16(uf[kt][q], hB, acc[q], 0, 0, 0);
    }

    // ---- gates + publish (relaxed 2B atomic stores, B-frag order) ----
    ushort* hw = hbuf + (size_t)((tau + 1) & 1) * HB_PAR_US + grp_us + (cg * 4 + nt) * 512;
#pragma unroll
    for (int q = 0; q < 4; ++q) {
      const float iv = sigf(acc[q][0]);
      const float fv = sigf(acc[q][1]);
      const float gv = tanhf_(acc[q][2]);
      const float ov = sigf(acc[q][3]);
      const float cn = fv * c_[q] + iv * gv;
      c_[q] = cn;
      const float hv = ov * tanhf_(cn);
      hm[q] = fmaxf(hm[q], hv);
      const int hdl = mh * 16 + q * 4 + (lane >> 4);
      const int lane2 = (lane & 15) | ((hdl >> 3) << 4);
      __hip_atomic_store(hw + lane2 * 8 + (hdl & 7), f2bf(hv),
                         __ATOMIC_RELAXED, __HIP_MEMORY_SCOPE_AGENT);
    }

    // ---- stage x_{tau+1} (off critical path) ----
    if (tau + 1 < NT) {
      const int t = dir ? (NT - 2 - tau) : (tau + 1);
      const ushort* xs = x + ((size_t)t * NB + b0 + xrow) * NE + (tx & 7) * 8;
#pragma unroll
      for (int i = 0; i < 4; ++i) {
        bf16x8 v = *(const bf16x8*)(xs + i * 64);
        const int c = (tx & 7) + 8 * i;
        *(bf16x8*)(smem + 65536 + xrow * 512 + ((c ^ (xrow & 7)) << 4)) = v;
      }
    }
    __syncthreads();                                    // (3) drains publish stores
    if (tx == 0)
      __hip_atomic_fetch_add(cgrp + tau, 1u, __ATOMIC_RELAXED, __HIP_MEMORY_SCOPE_AGENT);
  }

  // ---- maxpool output ----
#pragma unroll
  for (int q = 0; q < 4; ++q) {
    const int b = b0 + nt * 16 + (lane & 15);
    const int col = ll * 512 + dir * 256 + cg * 32 + mh * 16 + q * 4 + (lane >> 4);
    out[(size_t)b * 1536 + col] = hm[q];
  }
}

extern "C" void kernel_launch(void* const* d_in, const int* in_sizes, int n_in,
                              void* d_out, int out_size, void* d_ws, size_t ws_size,
                              hipStream_t stream) {
  (void)in_sizes; (void)n_in; (void)out_size; (void)ws_size;
  const int*   tokens = (const int*)d_in[0];
  const float* Emb    = (const float*)d_in[1];
  const float* Wf     = (const float*)d_in[2];
  const float* Uf     = (const float*)d_in[3];
  const float* bf_    = (const float*)d_in[4];
  const float* Wb     = (const float*)d_in[5];
  const float* Ub     = (const float*)d_in[6];
  const float* bb_    = (const float*)d_in[7];
  float* out = (float*)d_out;

  ushort* x    = (ushort*)((char*)d_ws + X_OFF);
  ushort* wt   = (ushort*)((char*)d_ws + WT_OFF);
  ushort* ut   = (ushort*)((char*)d_ws + UT_OFF);
  ushort* hbuf = (ushort*)((char*)d_ws + HB_OFF);
  uint*   cnt  = (uint*)((char*)d_ws + CNT_OFF);

  hipLaunchKernelGGL(k_embed, dim3((NB * NT) / 4), dim3(256), 0, stream, tokens, Emb, x);
  hipLaunchKernelGGL(k_pack, dim3(768), dim3(256), 0, stream, Wf, Uf, Wb, Ub, wt, ut);
  hipLaunchKernelGGL(k_init, dim3(387), dim3(256), 0, stream, (uint4*)hbuf);
  hipLaunchKernelGGL(k_lstm, dim3(192), dim3(512), 0, stream, x, wt, ut, bf_, bb_, hbuf, cnt, out);
}